// Round 5
// baseline (999.592 us; speedup 1.0000x reference)
//
#include <hip/hip_runtime.h>
#include <math.h>

typedef __bf16 bf16x8 __attribute__((ext_vector_type(8)));
typedef float f32x4 __attribute__((ext_vector_type(4)));
typedef float f32x16 __attribute__((ext_vector_type(16)));
typedef unsigned short ushort_t;
typedef unsigned int uint_t;

__device__ __forceinline__ ushort_t f2bf(float f) {
    uint_t u = __float_as_uint(f);
    u += 0x7fff + ((u >> 16) & 1);          // RNE
    return (ushort_t)(u >> 16);
}
__device__ __forceinline__ float bf2f(ushort_t h) {
    return __uint_as_float(((uint_t)h) << 16);
}

// Packed tile-major layout == the GEMM's LDS image, so staging is contiguous.
// element (row,k) -> ((band*(K/32)+kc)*512 + kq*128 + r)*8 + ki
//   band=row>>7, r=row&127, kc=k>>5, kq=(k>>3)&3, ki=k&7
__device__ __forceinline__ size_t poff(int row, int k, int Kdim) {
    return ((((size_t)(row >> 7) * (Kdim >> 5) + (k >> 5)) * 512)
            + ((k >> 3) & 3) * 128 + (row & 127)) * 8 + (k & 7);
}

// async global->LDS, 16B per lane. LDS dest is wave-uniform base + lane*16.
__device__ __forceinline__ void ll16(const ushort_t* g, ushort_t* l) {
    __builtin_amdgcn_global_load_lds(
        (const __attribute__((address_space(1))) unsigned int*)g,
        (__attribute__((address_space(3))) unsigned int*)l, 16, 0, 0);
}

template <int N> __device__ __forceinline__ void wait_vmcnt() {
    if constexpr (N == 0) asm volatile("s_waitcnt vmcnt(0)" ::: "memory");
    else if constexpr (N == 1) asm volatile("s_waitcnt vmcnt(1)" ::: "memory");
    else if constexpr (N == 2) asm volatile("s_waitcnt vmcnt(2)" ::: "memory");
    else if constexpr (N == 3) asm volatile("s_waitcnt vmcnt(3)" ::: "memory");
    else if constexpr (N == 4) asm volatile("s_waitcnt vmcnt(4)" ::: "memory");
    else if constexpr (N == 5) asm volatile("s_waitcnt vmcnt(5)" ::: "memory");
    else asm volatile("s_waitcnt vmcnt(6)" ::: "memory");
}

// ---- split x (row-major fp32) -> packed hi/lo bf16. one thread = 8 k ----
__global__ __launch_bounds__(256) void split_kernel(
    const float* __restrict__ in, ushort_t* __restrict__ hi,
    ushort_t* __restrict__ lo, int Kdim)
{
    const int i = blockIdx.x * 256 + threadIdx.x;
    const int row = i >> 8;            // Kdim==2048: 256 octets per row
    const int k = (i & 255) * 8;
    const float4 v0 = *(const float4*)(in + (size_t)row * Kdim + k);
    const float4 v1 = *(const float4*)(in + (size_t)row * Kdim + k + 4);
    const float f[8] = {v0.x, v0.y, v0.z, v0.w, v1.x, v1.y, v1.z, v1.w};
    ushort_t h[8], l[8];
    #pragma unroll
    for (int j = 0; j < 8; ++j) {
        h[j] = f2bf(f[j]);
        l[j] = f2bf(f[j] - bf2f(h[j]));
    }
    const size_t o = poff(row, k, Kdim);
    *(uint4*)(hi + o) = *(const uint4*)h;
    *(uint4*)(lo + o) = *(const uint4*)l;
}

// ---- transpose+split W [K,N] fp32 -> packed Wt over padded N rows ----
__global__ __launch_bounds__(256) void tsplit_kernel(
    const float* __restrict__ W, ushort_t* __restrict__ hi,
    ushort_t* __restrict__ lo, int K, int N, int write_lo)
{
    __shared__ float t[32][33];
    const int tx = threadIdx.x & 31;
    const int ty = threadIdx.x >> 5;
    const int nb = blockIdx.x * 32;
    const int kb = blockIdx.y * 32;
    #pragma unroll
    for (int i = 0; i < 4; ++i) {
        int k = kb + ty + i * 8;
        int n = nb + tx;
        t[ty + i * 8][tx] = (n < N) ? W[(size_t)k * N + n] : 0.f;
    }
    __syncthreads();
    #pragma unroll
    for (int i = 0; i < 4; ++i) {
        int n = nb + ty + i * 8;           // output row (padded space)
        int k = kb + tx;
        float f = t[tx][ty + i * 8];
        size_t idx = poff(n, k, K);
        ushort_t h = f2bf(f);
        hi[idx] = h;
        if (write_lo) lo[idx] = f2bf(f - bf2f(h));
    }
}

// =====================================================================
// 256-row-tile MFMA GEMMs, 512 threads = 8 waves (2 M x 4 N), phase-
// pipelined with counted vmcnt (never drained to 0 in steady state).
// MFMA shape: 32x32x16 bf16 (2382 TF ceiling vs 2075 for 16x16x32).
// Wave tile 128 x (BN/4): 4 M-frags x (BN/128) N-frags, f32x16 acc.
// Operand frag: lane reads row base+(l&31), 8 consecutive k at
// kq = ks*2 + (l>>5)  -> conflict-free ds_read_b128 on the packed slab.
// C/D: col = lane&31, row = (reg&3) + 8*(reg>>2) + 4*(lane>>5).
// =====================================================================

// ---- split precision: acc += Ah*Bh + Ah*Bl + Al*Bh ----
template <int BN>
__global__ __launch_bounds__(512, 2) void gemm_split3(
    const ushort_t* __restrict__ Ahi, const ushort_t* __restrict__ Alo,
    const ushort_t* __restrict__ Bhi, const ushort_t* __restrict__ Blo,
    const float* __restrict__ bias,
    float* __restrict__ Cf, ushort_t* __restrict__ Chi, ushort_t* __restrict__ Clo,
    int K, int Ntrue, int ldc, int relu_flag)
{
    static_assert(BN == 256 || BN == 128, "BN");
    constexpr int BSLAB = BN / 128;        // B slabs per K-tile
    constexpr int NF = BN / 128;           // 32-col N frags per wave
    constexpr int WS = BSLAB + 2;          // issues per half (hi == lo count)

    __shared__ __align__(16) ushort_t sAh[2][8192];
    __shared__ __align__(16) ushort_t sAl[2][8192];
    __shared__ __align__(16) ushort_t sBh[2][BSLAB * 4096];
    __shared__ __align__(16) ushort_t sBl[2][BSLAB * 4096];

    const int tid = threadIdx.x;
    const int m0 = blockIdx.y * 256;
    const int n0 = blockIdx.x * BN;

    const int lane = tid & 63, wave = tid >> 6;
    const int wm = wave >> 2, wn = wave & 3;   // 2 x 4 waves; wave tile 128 x (BN/4)
    const int r32 = lane & 31, kh = lane >> 5; // frag row, k-half
    const int wofs = wave * 512;               // staging: wave-uniform LDS base

    const size_t bstr = (size_t)(K >> 5) * 4096;   // band stride (elems)
    const ushort_t* gAh = Ahi + (size_t)(2 * blockIdx.y) * bstr + tid * 8;
    const ushort_t* gAl = Alo + (size_t)(2 * blockIdx.y) * bstr + tid * 8;
    const ushort_t* gBh = Bhi + (size_t)(BSLAB * blockIdx.x) * bstr + tid * 8;
    const ushort_t* gBl = Blo + (size_t)(BSLAB * blockIdx.x) * bstr + tid * 8;

    // frag LDS offsets: a/b[ks*count + idx], ks in {0,1} adds 2048 elems
    int aoff[8], boff[2 * NF];
    #pragma unroll
    for (int ks = 0; ks < 2; ++ks)
        #pragma unroll
        for (int mi = 0; mi < 4; ++mi)
            aoff[ks * 4 + mi] = wm * 4096 + (ks * 256 + kh * 128 + mi * 32 + r32) * 8;
    #pragma unroll
    for (int ks = 0; ks < 2; ++ks)
        #pragma unroll
        for (int nj = 0; nj < NF; ++nj) {
            const int c = wn * (BN / 4) + nj * 32 + r32;
            boff[ks * NF + nj] = (c >> 7) * 4096 + (ks * 256 + kh * 128 + (c & 127)) * 8;
        }

    f32x16 acc[4][NF];
    #pragma unroll
    for (int mi = 0; mi < 4; ++mi)
        #pragma unroll
        for (int nj = 0; nj < NF; ++nj) acc[mi][nj] = (f32x16)(0.f);

    const int NT = K >> 5;

    // prologue: stage tile 0 in phase order (hi | lo)
    ll16(gAh, &sAh[0][wofs]);
    ll16(gAh + bstr, &sAh[0][4096 + wofs]);
    ll16(gBh, &sBh[0][wofs]);
    if constexpr (BSLAB == 2) ll16(gBh + bstr, &sBh[0][4096 + wofs]);
    ll16(gBl, &sBl[0][wofs]);
    if constexpr (BSLAB == 2) ll16(gBl + bstr, &sBl[0][4096 + wofs]);
    ll16(gAl, &sAl[0][wofs]);
    ll16(gAl + bstr, &sAl[0][4096 + wofs]);

    bf16x8 ah[8], bh[2 * NF];
    for (int t = 0; t < NT - 1; ++t) {
        const int c = t & 1;
        const size_t ko = (size_t)(t + 1) * 4096;

        // ---- P0: Ah * Bh ----
        wait_vmcnt<WS>();                  // hi(t) landed; lo(t) may fly
        __builtin_amdgcn_s_barrier();
        #pragma unroll
        for (int f = 0; f < 8; ++f) ah[f] = *(const bf16x8*)(&sAh[c][aoff[f]]);
        #pragma unroll
        for (int f = 0; f < 2 * NF; ++f) bh[f] = *(const bf16x8*)(&sBh[c][boff[f]]);
        ll16(gAh + ko, &sAh[c ^ 1][wofs]);
        ll16(gAh + bstr + ko, &sAh[c ^ 1][4096 + wofs]);
        ll16(gBh + ko, &sBh[c ^ 1][wofs]);
        if constexpr (BSLAB == 2) ll16(gBh + bstr + ko, &sBh[c ^ 1][4096 + wofs]);
        __builtin_amdgcn_sched_barrier(0);   // staging issues stay ahead of MFMA
        __builtin_amdgcn_s_setprio(1);
        #pragma unroll
        for (int ks = 0; ks < 2; ++ks)
            #pragma unroll
            for (int nj = 0; nj < NF; ++nj)
                #pragma unroll
                for (int mi = 0; mi < 4; ++mi)
                    acc[mi][nj] = __builtin_amdgcn_mfma_f32_32x32x16_bf16(
                        ah[ks * 4 + mi], bh[ks * NF + nj], acc[mi][nj], 0, 0, 0);
        __builtin_amdgcn_s_setprio(0);

        // ---- P12: Ah * Bl then Al * Bh (one cluster, one barrier) ----
        wait_vmcnt<WS>();                  // lo(t) landed; hi(t+1) may fly
        __builtin_amdgcn_s_barrier();
        bf16x8 bl[2 * NF];
        #pragma unroll
        for (int f = 0; f < 2 * NF; ++f) bl[f] = *(const bf16x8*)(&sBl[c][boff[f]]);
        bf16x8 al[8];
        #pragma unroll
        for (int f = 0; f < 8; ++f) al[f] = *(const bf16x8*)(&sAl[c][aoff[f]]);
        ll16(gBl + ko, &sBl[c ^ 1][wofs]);
        if constexpr (BSLAB == 2) ll16(gBl + bstr + ko, &sBl[c ^ 1][4096 + wofs]);
        ll16(gAl + ko, &sAl[c ^ 1][wofs]);
        ll16(gAl + bstr + ko, &sAl[c ^ 1][4096 + wofs]);
        __builtin_amdgcn_sched_barrier(0);
        __builtin_amdgcn_s_setprio(1);
        #pragma unroll
        for (int ks = 0; ks < 2; ++ks)
            #pragma unroll
            for (int nj = 0; nj < NF; ++nj)
                #pragma unroll
                for (int mi = 0; mi < 4; ++mi)
                    acc[mi][nj] = __builtin_amdgcn_mfma_f32_32x32x16_bf16(
                        ah[ks * 4 + mi], bl[ks * NF + nj], acc[mi][nj], 0, 0, 0);
        #pragma unroll
        for (int ks = 0; ks < 2; ++ks)
            #pragma unroll
            for (int nj = 0; nj < NF; ++nj)
                #pragma unroll
                for (int mi = 0; mi < 4; ++mi)
                    acc[mi][nj] = __builtin_amdgcn_mfma_f32_32x32x16_bf16(
                        al[ks * 4 + mi], bh[ks * NF + nj], acc[mi][nj], 0, 0, 0);
        __builtin_amdgcn_s_setprio(0);
    }

    // ---- tail tile NT-1 (no staging; counted drain WS/0) ----
    {
        const int c = (NT - 1) & 1;
        wait_vmcnt<WS>();
        __builtin_amdgcn_s_barrier();
        #pragma unroll
        for (int f = 0; f < 8; ++f) ah[f] = *(const bf16x8*)(&sAh[c][aoff[f]]);
        #pragma unroll
        for (int f = 0; f < 2 * NF; ++f) bh[f] = *(const bf16x8*)(&sBh[c][boff[f]]);
        __builtin_amdgcn_s_setprio(1);
        #pragma unroll
        for (int ks = 0; ks < 2; ++ks)
            #pragma unroll
            for (int nj = 0; nj < NF; ++nj)
                #pragma unroll
                for (int mi = 0; mi < 4; ++mi)
                    acc[mi][nj] = __builtin_amdgcn_mfma_f32_32x32x16_bf16(
                        ah[ks * 4 + mi], bh[ks * NF + nj], acc[mi][nj], 0, 0, 0);
        __builtin_amdgcn_s_setprio(0);

        wait_vmcnt<0>();
        __builtin_amdgcn_s_barrier();
        bf16x8 bl[2 * NF];
        #pragma unroll
        for (int f = 0; f < 2 * NF; ++f) bl[f] = *(const bf16x8*)(&sBl[c][boff[f]]);
        bf16x8 al[8];
        #pragma unroll
        for (int f = 0; f < 8; ++f) al[f] = *(const bf16x8*)(&sAl[c][aoff[f]]);
        __builtin_amdgcn_s_setprio(1);
        #pragma unroll
        for (int ks = 0; ks < 2; ++ks)
            #pragma unroll
            for (int nj = 0; nj < NF; ++nj)
                #pragma unroll
                for (int mi = 0; mi < 4; ++mi)
                    acc[mi][nj] = __builtin_amdgcn_mfma_f32_32x32x16_bf16(
                        ah[ks * 4 + mi], bl[ks * NF + nj], acc[mi][nj], 0, 0, 0);
        #pragma unroll
        for (int ks = 0; ks < 2; ++ks)
            #pragma unroll
            for (int nj = 0; nj < NF; ++nj)
                #pragma unroll
                for (int mi = 0; mi < 4; ++mi)
                    acc[mi][nj] = __builtin_amdgcn_mfma_f32_32x32x16_bf16(
                        al[ks * 4 + mi], bh[ks * NF + nj], acc[mi][nj], 0, 0, 0);
        __builtin_amdgcn_s_setprio(0);
    }

    // epilogue: per 32x32 tile, col = r32, row = (reg&3)+8*(reg>>2)+4*kh
    #pragma unroll
    for (int mi = 0; mi < 4; ++mi) {
        #pragma unroll
        for (int nj = 0; nj < NF; ++nj) {
            const int col = n0 + wn * (BN / 4) + nj * 32 + r32;
            const int rowb = m0 + wm * 128 + mi * 32 + 4 * kh;
            const float bv = (col < Ntrue) ? bias[col] : 0.f;
            #pragma unroll
            for (int reg = 0; reg < 16; ++reg) {
                const int row = rowb + (reg & 3) + 8 * (reg >> 2);
                float v = acc[mi][nj][reg] + bv;
                if (relu_flag) v = fmaxf(v, 0.f);
                if (Cf) {
                    if (col < Ntrue) Cf[(size_t)row * ldc + col] = v;
                } else {
                    const size_t idx = poff(row, col, ldc);  // packed dest
                    ushort_t h = f2bf(v);
                    Chi[idx] = h;
                    Clo[idx] = f2bf(v - bf2f(h));
                }
            }
        }
    }
}

// ---- plain bf16 single pass: quad-buffered, 2-tile-ahead prefetch ----
template <int BN>
__global__ __launch_bounds__(512, 2) void gemm_bf16k(
    const ushort_t* __restrict__ Ahi, const ushort_t* __restrict__ Bhi,
    const float* __restrict__ bias,
    float* __restrict__ Cf, ushort_t* __restrict__ Chi,
    int K, int Ntrue, int ldc, int relu_flag)
{
    static_assert(BN == 256 || BN == 128, "BN");
    constexpr int BSLAB = BN / 128;
    constexpr int NF = BN / 128;
    constexpr int SH = 2 + BSLAB;          // issues per tile

    __shared__ __align__(16) ushort_t sA[4][8192];
    __shared__ __align__(16) ushort_t sB[4][BSLAB * 4096];

    const int tid = threadIdx.x;
    const int m0 = blockIdx.y * 256;
    const int n0 = blockIdx.x * BN;

    const int lane = tid & 63, wave = tid >> 6;
    const int wm = wave >> 2, wn = wave & 3;
    const int r32 = lane & 31, kh = lane >> 5;
    const int wofs = wave * 512;

    const size_t bstr = (size_t)(K >> 5) * 4096;
    const ushort_t* gA = Ahi + (size_t)(2 * blockIdx.y) * bstr + tid * 8;
    const ushort_t* gB = Bhi + (size_t)(BSLAB * blockIdx.x) * bstr + tid * 8;

    int aoff[8], boff[2 * NF];
    #pragma unroll
    for (int ks = 0; ks < 2; ++ks)
        #pragma unroll
        for (int mi = 0; mi < 4; ++mi)
            aoff[ks * 4 + mi] = wm * 4096 + (ks * 256 + kh * 128 + mi * 32 + r32) * 8;
    #pragma unroll
    for (int ks = 0; ks < 2; ++ks)
        #pragma unroll
        for (int nj = 0; nj < NF; ++nj) {
            const int c = wn * (BN / 4) + nj * 32 + r32;
            boff[ks * NF + nj] = (c >> 7) * 4096 + (ks * 256 + kh * 128 + (c & 127)) * 8;
        }

    f32x16 acc[4][NF];
    #pragma unroll
    for (int mi = 0; mi < 4; ++mi)
        #pragma unroll
        for (int nj = 0; nj < NF; ++nj) acc[mi][nj] = (f32x16)(0.f);

    const int NT = K >> 5;

    // prologue: stage tiles 0 and 1
    #pragma unroll
    for (int tt = 0; tt < 2; ++tt) {
        const size_t ko = (size_t)tt * 4096;
        ll16(gA + ko, &sA[tt][wofs]);
        ll16(gA + bstr + ko, &sA[tt][4096 + wofs]);
        ll16(gB + ko, &sB[tt][wofs]);
        if constexpr (BSLAB == 2) ll16(gB + bstr + ko, &sB[tt][4096 + wofs]);
    }

    bf16x8 ah[8], bh[2 * NF];
    for (int t = 0; t < NT - 1; ++t) {
        const int c = t & 3;
        wait_vmcnt<SH>();                  // tile t landed; t+1 may fly
        __builtin_amdgcn_s_barrier();
        #pragma unroll
        for (int f = 0; f < 8; ++f) ah[f] = *(const bf16x8*)(&sA[c][aoff[f]]);
        #pragma unroll
        for (int f = 0; f < 2 * NF; ++f) bh[f] = *(const bf16x8*)(&sB[c][boff[f]]);
        if (t + 2 < NT) {
            const int c2 = (t + 2) & 3;
            const size_t ko = (size_t)(t + 2) * 4096;
            ll16(gA + ko, &sA[c2][wofs]);
            ll16(gA + bstr + ko, &sA[c2][4096 + wofs]);
            ll16(gB + ko, &sB[c2][wofs]);
            if constexpr (BSLAB == 2) ll16(gB + bstr + ko, &sB[c2][4096 + wofs]);
        }
        __builtin_amdgcn_sched_barrier(0);
        __builtin_amdgcn_s_setprio(1);
        #pragma unroll
        for (int ks = 0; ks < 2; ++ks)
            #pragma unroll
            for (int nj = 0; nj < NF; ++nj)
                #pragma unroll
                for (int mi = 0; mi < 4; ++mi)
                    acc[mi][nj] = __builtin_amdgcn_mfma_f32_32x32x16_bf16(
                        ah[ks * 4 + mi], bh[ks * NF + nj], acc[mi][nj], 0, 0, 0);
        __builtin_amdgcn_s_setprio(0);
    }
    {   // tail tile NT-1
        const int c = (NT - 1) & 3;
        wait_vmcnt<0>();
        __builtin_amdgcn_s_barrier();
        #pragma unroll
        for (int f = 0; f < 8; ++f) ah[f] = *(const bf16x8*)(&sA[c][aoff[f]]);
        #pragma unroll
        for (int f = 0; f < 2 * NF; ++f) bh[f] = *(const bf16x8*)(&sB[c][boff[f]]);
        __builtin_amdgcn_s_setprio(1);
        #pragma unroll
        for (int ks = 0; ks < 2; ++ks)
            #pragma unroll
            for (int nj = 0; nj < NF; ++nj)
                #pragma unroll
                for (int mi = 0; mi < 4; ++mi)
                    acc[mi][nj] = __builtin_amdgcn_mfma_f32_32x32x16_bf16(
                        ah[ks * 4 + mi], bh[ks * NF + nj], acc[mi][nj], 0, 0, 0);
        __builtin_amdgcn_s_setprio(0);
    }

    #pragma unroll
    for (int mi = 0; mi < 4; ++mi) {
        #pragma unroll
        for (int nj = 0; nj < NF; ++nj) {
            const int col = n0 + wn * (BN / 4) + nj * 32 + r32;
            const int rowb = m0 + wm * 128 + mi * 32 + 4 * kh;
            const float bv = (col < Ntrue) ? bias[col] : 0.f;
            #pragma unroll
            for (int reg = 0; reg < 16; ++reg) {
                const int row = rowb + (reg & 3) + 8 * (reg >> 2);
                float v = acc[mi][nj][reg] + bv;
                if (relu_flag) v = fmaxf(v, 0.f);
                if (Cf) {
                    if (col < Ntrue) Cf[(size_t)row * ldc + col] = v;
                } else {
                    const size_t idx = poff(row, col, ldc);
                    Chi[idx] = f2bf(v);
                }
            }
        }
    }
}

// ---- finalize: per-row confidence cascade + output select ----
// confident <=> max softmax prob > 0.01 <=> sum(exp(l - max)) < 100
// out holds p1. If conf1: keep. Else if conf2: out = p2 row. Else: out = p3.
__global__ __launch_bounds__(256) void finalize_kernel(
    float* __restrict__ out, const float* __restrict__ p2,
    const float* __restrict__ p3, int N)
{
    __shared__ float rm[4];
    __shared__ float rs[4];
    const int b = blockIdx.x;
    const int wv = threadIdx.x >> 6, ln = threadIdx.x & 63;

    // conf on p1 (== out row)
    const float* row = out + (size_t)b * N;
    float m = -3.0e38f;
    for (int c = threadIdx.x; c < N; c += 256) m = fmaxf(m, row[c]);
    #pragma unroll
    for (int off = 32; off > 0; off >>= 1) m = fmaxf(m, __shfl_down(m, off));
    if (ln == 0) rm[wv] = m;
    __syncthreads();
    m = fmaxf(fmaxf(rm[0], rm[1]), fmaxf(rm[2], rm[3]));
    float s = 0.f;
    for (int c = threadIdx.x; c < N; c += 256) s += expf(row[c] - m);
    #pragma unroll
    for (int off = 32; off > 0; off >>= 1) s += __shfl_down(s, off);
    if (ln == 0) rs[wv] = s;
    __syncthreads();
    const float tot1 = rs[0] + rs[1] + rs[2] + rs[3];
    if (tot1 < 100.0f) return;             // stage-1 exit: keep p1

    // conf on p2
    __syncthreads();                       // protect rm/rs reuse
    const float* row2 = p2 + (size_t)b * N;
    m = -3.0e38f;
    for (int c = threadIdx.x; c < N; c += 256) m = fmaxf(m, row2[c]);
    #pragma unroll
    for (int off = 32; off > 0; off >>= 1) m = fmaxf(m, __shfl_down(m, off));
    if (ln == 0) rm[wv] = m;
    __syncthreads();
    m = fmaxf(fmaxf(rm[0], rm[1]), fmaxf(rm[2], rm[3]));
    s = 0.f;
    for (int c = threadIdx.x; c < N; c += 256) s += expf(row2[c] - m);
    #pragma unroll
    for (int off = 32; off > 0; off >>= 1) s += __shfl_down(s, off);
    if (ln == 0) rs[wv] = s;
    __syncthreads();
    const float tot2 = rs[0] + rs[1] + rs[2] + rs[3];

    const float* src = (tot2 < 100.0f) ? row2 : (p3 + (size_t)b * N);
    float* dst = out + (size_t)b * N;
    // N == 1000: 250 float4 per row, rows 16B-aligned (4000B stride)
    for (int c4 = threadIdx.x; c4 < (N >> 2); c4 += 256)
        ((float4*)dst)[c4] = ((const float4*)src)[c4];
    for (int c = (N & ~3) + threadIdx.x; c < N; c += 256) dst[c] = src[c];
}

extern "C" void kernel_launch(void* const* d_in, const int* in_sizes, int n_in,
                              void* d_out, int out_size, void* d_ws, size_t ws_size,
                              hipStream_t stream)
{
    const float* x   = (const float*)d_in[0];
    const float* W1  = (const float*)d_in[1];
    const float* b1  = (const float*)d_in[2];
    const float* W2  = (const float*)d_in[3];
    const float* b2  = (const float*)d_in[4];
    const float* W3  = (const float*)d_in[5];
    const float* b3  = (const float*)d_in[6];
    const float* H1w = (const float*)d_in[7];
    const float* H1b = (const float*)d_in[8];
    const float* H2w = (const float*)d_in[9];
    const float* H2b = (const float*)d_in[10];
    const float* Fw  = (const float*)d_in[11];
    const float* Fb  = (const float*)d_in[12];
    float* out = (float*)d_out;

    const int B = 8192, D = 2048, Hh = 2048, Cc = 1000;

    // ---- workspace carve (~184 MB; ushort units) ----
    ushort_t* xhi  = (ushort_t*)d_ws;             // B*D packed x-hi   (-> h2-hi)
    ushort_t* xlo  = xhi + (size_t)B * D;         // B*D packed x-lo   (-> h2-lo -> p3 fp32)
    ushort_t* h1hi = xlo + (size_t)B * D;         // B*H packed h1-hi  (-> h3-hi)
    ushort_t* h1lo = h1hi + (size_t)B * Hh;       // B*H packed h1-lo
    ushort_t* W0hi = h1lo + (size_t)B * Hh;       // 2048x2048 packed (W1t/W2t/W3t)
    ushort_t* W0lo = W0hi + (size_t)Hh * Hh;
    ushort_t* W1thi = W0lo + (size_t)Hh * Hh;     // 1024x2048 packed (heads)
    ushort_t* W1tlo = W1thi + (size_t)1024 * Hh;
    float* p2 = (float*)(W1tlo + (size_t)1024 * Hh);  // B*Cc fp32

    ushort_t* h2hi = xhi;  ushort_t* h2lo = xlo;   // x dead after stage-1 backbone
    ushort_t* h3hi = h1hi;                          // h1 dead after stage-2 backbone
    float* p3 = (float*)xlo;                        // h2-lo dead after stage-2 head

    dim3 blk(256);
    dim3 blk5(512);
    const dim3 gBB(Hh / 256, B / 256);   // backbone GEMM: 256x256 tiles (8, 32)
    const dim3 gHD(1024 / 128, B / 256); // head GEMM: 256x128 tiles (8, 32)
    const dim3 gT2(64, 64);   // tsplit 2048x2048
    const dim3 gTH(32, 64);   // tsplit head (Npad=1024)

    // Stage 1
    split_kernel<<<dim3(B * D / 8 / 256), blk, 0, stream>>>(x, xhi, xlo, D);
    tsplit_kernel<<<gT2, blk, 0, stream>>>(W1, W0hi, W0lo, D, Hh, 1);
    gemm_split3<256><<<gBB, blk5, 0, stream>>>(xhi, xlo, W0hi, W0lo, b1,
                                               nullptr, h1hi, h1lo, D, Hh, Hh, 1);
    tsplit_kernel<<<gTH, blk, 0, stream>>>(H1w, W1thi, W1tlo, Hh, Cc, 1);
    gemm_split3<128><<<gHD, blk5, 0, stream>>>(h1hi, h1lo, W1thi, W1tlo, H1b,
                                               out, nullptr, nullptr, Hh, Cc, Cc, 0);

    // Stage 2 (all rows; exits are rare so dense is cheaper than compaction)
    tsplit_kernel<<<gT2, blk, 0, stream>>>(W2, W0hi, W0lo, Hh, Hh, 1);
    gemm_split3<256><<<gBB, blk5, 0, stream>>>(h1hi, h1lo, W0hi, W0lo, b2,
                                               nullptr, h2hi, h2lo, Hh, Hh, Hh, 1);
    tsplit_kernel<<<gTH, blk, 0, stream>>>(H2w, W1thi, W1tlo, Hh, Cc, 1);
    gemm_split3<128><<<gHD, blk5, 0, stream>>>(h2hi, h2lo, W1thi, W1tlo, H2b,
                                               p2, nullptr, nullptr, Hh, Cc, Cc, 0);

    // Stage 3 (all rows; plain bf16 single pass)
    tsplit_kernel<<<gT2, blk, 0, stream>>>(W3, W0hi, nullptr, Hh, Hh, 0);
    gemm_bf16k<256><<<gBB, blk5, 0, stream>>>(h2hi, W0hi, b3,
                                              nullptr, h3hi, Hh, Hh, Hh, 1);
    tsplit_kernel<<<gTH, blk, 0, stream>>>(Fw, W1thi, nullptr, Hh, Cc, 0);
    gemm_bf16k<128><<<gHD, blk5, 0, stream>>>(h3hi, W1thi, Fb,
                                              p3, nullptr, Hh, Cc, Cc, 0);

    // Merge: per-row confidence cascade, select p1/p2/p3 into out
    finalize_kernel<<<dim3(B), blk, 0, stream>>>(out, p2, p3, Cc);
}

// Round 7
// 876.704 us; speedup vs baseline: 1.1402x; 1.1402x over previous
//
#include <hip/hip_runtime.h>
#include <math.h>

typedef __bf16 bf16x8 __attribute__((ext_vector_type(8)));
typedef float f32x4 __attribute__((ext_vector_type(4)));
typedef unsigned short ushort_t;
typedef unsigned int uint_t;

__device__ __forceinline__ ushort_t f2bf(float f) {
    uint_t u = __float_as_uint(f);
    u += 0x7fff + ((u >> 16) & 1);          // RNE
    return (ushort_t)(u >> 16);
}
__device__ __forceinline__ float bf2f(ushort_t h) {
    return __uint_as_float(((uint_t)h) << 16);
}

// Packed tile-major layout == the GEMM's LDS image, so staging is contiguous.
// element (row,k) -> ((band*(K/32)+kc)*512 + kq*128 + r)*8 + ki
//   band=row>>7, r=row&127, kc=k>>5, kq=(k>>3)&3, ki=k&7
__device__ __forceinline__ size_t poff(int row, int k, int Kdim) {
    return ((((size_t)(row >> 7) * (Kdim >> 5) + (k >> 5)) * 512)
            + ((k >> 3) & 3) * 128 + (row & 127)) * 8 + (k & 7);
}

// async global->LDS, 16B per lane. LDS dest is wave-uniform base + lane*16.
__device__ __forceinline__ void ll16(const ushort_t* g, ushort_t* l) {
    __builtin_amdgcn_global_load_lds(
        (const __attribute__((address_space(1))) unsigned int*)g,
        (__attribute__((address_space(3))) unsigned int*)l, 16, 0, 0);
}

template <int N> __device__ __forceinline__ void wait_vmcnt() {
    if constexpr (N == 0) asm volatile("s_waitcnt vmcnt(0)" ::: "memory");
    else if constexpr (N == 1) asm volatile("s_waitcnt vmcnt(1)" ::: "memory");
    else if constexpr (N == 2) asm volatile("s_waitcnt vmcnt(2)" ::: "memory");
    else if constexpr (N == 3) asm volatile("s_waitcnt vmcnt(3)" ::: "memory");
    else if constexpr (N == 4) asm volatile("s_waitcnt vmcnt(4)" ::: "memory");
    else if constexpr (N == 5) asm volatile("s_waitcnt vmcnt(5)" ::: "memory");
    else asm volatile("s_waitcnt vmcnt(6)" ::: "memory");
}

// XCD-aware block remap for an (8, 32) x-fastest grid: 8 XCDs round-robin on
// flat workgroup id, so give each XCD a 4x8 rectangle of (bx, by) tiles.
// Per-XCD distinct panels: 4 B + 8 A (~24 MB total, ~384 KB live per K-step)
// instead of 1 B + 32 A (~69 MB). Bijective; perf heuristic only.
__device__ __forceinline__ void xcd_remap(int& bx, int& by) {
    if (gridDim.x == 8 && gridDim.y == 32) {
        const int flat = blockIdx.y * 8 + blockIdx.x;
        const int xcd = flat & 7;
        const int j = flat >> 3;           // 0..31 within XCD
        bx = (xcd & 1) * 4 + (j & 3);
        by = (xcd >> 1) * 8 + (j >> 2);
    } else {
        bx = blockIdx.x; by = blockIdx.y;
    }
}

// ---- split x (row-major fp32) -> packed hi/lo bf16. one thread = 8 k ----
__global__ __launch_bounds__(256) void split_kernel(
    const float* __restrict__ in, ushort_t* __restrict__ hi,
    ushort_t* __restrict__ lo, int Kdim)
{
    const int i = blockIdx.x * 256 + threadIdx.x;
    const int row = i >> 8;            // Kdim==2048: 256 octets per row
    const int k = (i & 255) * 8;
    const float4 v0 = *(const float4*)(in + (size_t)row * Kdim + k);
    const float4 v1 = *(const float4*)(in + (size_t)row * Kdim + k + 4);
    const float f[8] = {v0.x, v0.y, v0.z, v0.w, v1.x, v1.y, v1.z, v1.w};
    ushort_t h[8], l[8];
    #pragma unroll
    for (int j = 0; j < 8; ++j) {
        h[j] = f2bf(f[j]);
        l[j] = f2bf(f[j] - bf2f(h[j]));
    }
    const size_t o = poff(row, k, Kdim);
    *(uint4*)(hi + o) = *(const uint4*)h;
    *(uint4*)(lo + o) = *(const uint4*)l;
}

// ---- transpose+split W [K,N] fp32 -> packed Wt over padded N rows ----
__global__ __launch_bounds__(256) void tsplit_kernel(
    const float* __restrict__ W, ushort_t* __restrict__ hi,
    ushort_t* __restrict__ lo, int K, int N, int write_lo)
{
    __shared__ float t[32][33];
    const int tx = threadIdx.x & 31;
    const int ty = threadIdx.x >> 5;
    const int nb = blockIdx.x * 32;
    const int kb = blockIdx.y * 32;
    #pragma unroll
    for (int i = 0; i < 4; ++i) {
        int k = kb + ty + i * 8;
        int n = nb + tx;
        t[ty + i * 8][tx] = (n < N) ? W[(size_t)k * N + n] : 0.f;
    }
    __syncthreads();
    #pragma unroll
    for (int i = 0; i < 4; ++i) {
        int n = nb + ty + i * 8;           // output row (padded space)
        int k = kb + tx;
        float f = t[tx][ty + i * 8];
        size_t idx = poff(n, k, K);
        ushort_t h = f2bf(f);
        hi[idx] = h;
        if (write_lo) lo[idx] = f2bf(f - bf2f(h));
    }
}

// =====================================================================
// 256-row-tile MFMA GEMMs, 512 threads = 8 waves (2 M x 4 N), phase-
// pipelined with counted vmcnt (never drained to 0 in steady state).
// Two phases per 32-K tile: P0 = Ah*Bh (stage hi(t+1)); P12 = Ah*Bl then
// Al*Bh in one 2x cluster (stage lo(t+1)). 16x16x32 MFMA (32x32x16 was
// measured SLOWER here: shorter clusters don't cover per-phase overhead).
// =====================================================================

// ---- split precision: acc += Ah*Bh + Ah*Bl + Al*Bh ----
template <int BN>
__global__ __launch_bounds__(512, 2) void gemm_split3(
    const ushort_t* __restrict__ Ahi, const ushort_t* __restrict__ Alo,
    const ushort_t* __restrict__ Bhi, const ushort_t* __restrict__ Blo,
    const float* __restrict__ bias,
    float* __restrict__ Cf, ushort_t* __restrict__ Chi, ushort_t* __restrict__ Clo,
    int K, int Ntrue, int ldc, int relu_flag)
{
    static_assert(BN == 256 || BN == 128, "BN");
    constexpr int BSLAB = BN / 128;        // B slabs per K-tile
    constexpr int NF = BN / 64;            // N fragments per wave
    constexpr int WS = BSLAB + 2;          // issues per half (hi == lo count)

    __shared__ __align__(16) ushort_t sAh[2][8192];
    __shared__ __align__(16) ushort_t sAl[2][8192];
    __shared__ __align__(16) ushort_t sBh[2][BSLAB * 4096];
    __shared__ __align__(16) ushort_t sBl[2][BSLAB * 4096];

    const int tid = threadIdx.x;
    int bx, by;
    xcd_remap(bx, by);
    const int m0 = by * 256;
    const int n0 = bx * BN;

    const int lane = tid & 63, wave = tid >> 6;
    const int wm = wave >> 2, wn = wave & 3;   // 2 x 4 waves; wave tile 128 x (BN/4)
    const int q = lane >> 4, r16 = lane & 15;
    const int wofs = wave * 512;               // staging: wave-uniform LDS base

    const size_t bstr = (size_t)(K >> 5) * 4096;   // band stride (elems)
    const ushort_t* gAh = Ahi + (size_t)(2 * by) * bstr + tid * 8;
    const ushort_t* gAl = Alo + (size_t)(2 * by) * bstr + tid * 8;
    const ushort_t* gBh = Bhi + (size_t)(BSLAB * bx) * bstr + tid * 8;
    const ushort_t* gBl = Blo + (size_t)(BSLAB * bx) * bstr + tid * 8;

    int aoff[8], boff[NF];
    #pragma unroll
    for (int mi = 0; mi < 8; ++mi)
        aoff[mi] = wm * 4096 + (q * 128 + mi * 16 + r16) * 8;
    #pragma unroll
    for (int nj = 0; nj < NF; ++nj) {
        const int col = wn * (NF * 16) + nj * 16 + r16;
        boff[nj] = (col >> 7) * 4096 + (q * 128 + (col & 127)) * 8;
    }

    f32x4 acc[8][NF];
    #pragma unroll
    for (int mi = 0; mi < 8; ++mi)
        #pragma unroll
        for (int nj = 0; nj < NF; ++nj) acc[mi][nj] = (f32x4)(0.f);

    const int NT = K >> 5;

    // prologue: stage tile 0 in phase order (hi | lo)
    ll16(gAh, &sAh[0][wofs]);
    ll16(gAh + bstr, &sAh[0][4096 + wofs]);
    ll16(gBh, &sBh[0][wofs]);
    if constexpr (BSLAB == 2) ll16(gBh + bstr, &sBh[0][4096 + wofs]);
    ll16(gBl, &sBl[0][wofs]);
    if constexpr (BSLAB == 2) ll16(gBl + bstr, &sBl[0][4096 + wofs]);
    ll16(gAl, &sAl[0][wofs]);
    ll16(gAl + bstr, &sAl[0][4096 + wofs]);

    bf16x8 ah[8], bh[NF];
    for (int t = 0; t < NT - 1; ++t) {
        const int c = t & 1;
        const size_t ko = (size_t)(t + 1) * 4096;

        // ---- P0: Ah * Bh ----
        wait_vmcnt<WS>();                  // hi(t) landed; lo(t) may fly
        __builtin_amdgcn_s_barrier();
        #pragma unroll
        for (int mi = 0; mi < 8; ++mi) ah[mi] = *(const bf16x8*)(&sAh[c][aoff[mi]]);
        #pragma unroll
        for (int nj = 0; nj < NF; ++nj) bh[nj] = *(const bf16x8*)(&sBh[c][boff[nj]]);
        ll16(gAh + ko, &sAh[c ^ 1][wofs]);
        ll16(gAh + bstr + ko, &sAh[c ^ 1][4096 + wofs]);
        ll16(gBh + ko, &sBh[c ^ 1][wofs]);
        if constexpr (BSLAB == 2) ll16(gBh + bstr + ko, &sBh[c ^ 1][4096 + wofs]);
        __builtin_amdgcn_sched_barrier(0);   // staging issues stay ahead of MFMA
        __builtin_amdgcn_s_setprio(1);
        #pragma unroll
        for (int nj = 0; nj < NF; ++nj)
            #pragma unroll
            for (int mi = 0; mi < 8; ++mi)
                acc[mi][nj] = __builtin_amdgcn_mfma_f32_16x16x32_bf16(ah[mi], bh[nj], acc[mi][nj], 0, 0, 0);
        __builtin_amdgcn_s_setprio(0);

        // ---- P12: Ah * Bl then Al * Bh (one cluster, one barrier) ----
        wait_vmcnt<WS>();                  // lo(t) landed; hi(t+1) may fly
        __builtin_amdgcn_s_barrier();
        bf16x8 bl[NF];
        #pragma unroll
        for (int nj = 0; nj < NF; ++nj) bl[nj] = *(const bf16x8*)(&sBl[c][boff[nj]]);
        bf16x8 al[8];
        #pragma unroll
        for (int mi = 0; mi < 8; ++mi) al[mi] = *(const bf16x8*)(&sAl[c][aoff[mi]]);
        ll16(gBl + ko, &sBl[c ^ 1][wofs]);
        if constexpr (BSLAB == 2) ll16(gBl + bstr + ko, &sBl[c ^ 1][4096 + wofs]);
        ll16(gAl + ko, &sAl[c ^ 1][wofs]);
        ll16(gAl + bstr + ko, &sAl[c ^ 1][4096 + wofs]);
        __builtin_amdgcn_sched_barrier(0);
        __builtin_amdgcn_s_setprio(1);
        #pragma unroll
        for (int nj = 0; nj < NF; ++nj)
            #pragma unroll
            for (int mi = 0; mi < 8; ++mi)
                acc[mi][nj] = __builtin_amdgcn_mfma_f32_16x16x32_bf16(ah[mi], bl[nj], acc[mi][nj], 0, 0, 0);
        #pragma unroll
        for (int nj = 0; nj < NF; ++nj)
            #pragma unroll
            for (int mi = 0; mi < 8; ++mi)
                acc[mi][nj] = __builtin_amdgcn_mfma_f32_16x16x32_bf16(al[mi], bh[nj], acc[mi][nj], 0, 0, 0);
        __builtin_amdgcn_s_setprio(0);
    }

    // ---- tail tile NT-1 (no staging; counted drain WS/0) ----
    {
        const int c = (NT - 1) & 1;
        wait_vmcnt<WS>();
        __builtin_amdgcn_s_barrier();
        #pragma unroll
        for (int mi = 0; mi < 8; ++mi) ah[mi] = *(const bf16x8*)(&sAh[c][aoff[mi]]);
        #pragma unroll
        for (int nj = 0; nj < NF; ++nj) bh[nj] = *(const bf16x8*)(&sBh[c][boff[nj]]);
        __builtin_amdgcn_s_setprio(1);
        #pragma unroll
        for (int nj = 0; nj < NF; ++nj)
            #pragma unroll
            for (int mi = 0; mi < 8; ++mi)
                acc[mi][nj] = __builtin_amdgcn_mfma_f32_16x16x32_bf16(ah[mi], bh[nj], acc[mi][nj], 0, 0, 0);
        __builtin_amdgcn_s_setprio(0);

        wait_vmcnt<0>();
        __builtin_amdgcn_s_barrier();
        bf16x8 bl[NF];
        #pragma unroll
        for (int nj = 0; nj < NF; ++nj) bl[nj] = *(const bf16x8*)(&sBl[c][boff[nj]]);
        bf16x8 al[8];
        #pragma unroll
        for (int mi = 0; mi < 8; ++mi) al[mi] = *(const bf16x8*)(&sAl[c][aoff[mi]]);
        __builtin_amdgcn_s_setprio(1);
        #pragma unroll
        for (int nj = 0; nj < NF; ++nj)
            #pragma unroll
            for (int mi = 0; mi < 8; ++mi)
                acc[mi][nj] = __builtin_amdgcn_mfma_f32_16x16x32_bf16(ah[mi], bl[nj], acc[mi][nj], 0, 0, 0);
        #pragma unroll
        for (int nj = 0; nj < NF; ++nj)
            #pragma unroll
            for (int mi = 0; mi < 8; ++mi)
                acc[mi][nj] = __builtin_amdgcn_mfma_f32_16x16x32_bf16(al[mi], bh[nj], acc[mi][nj], 0, 0, 0);
        __builtin_amdgcn_s_setprio(0);
    }

    // epilogue: per 16x16 tile, row = q*4 + r, col = r16
    #pragma unroll
    for (int mi = 0; mi < 8; ++mi) {
        #pragma unroll
        for (int nj = 0; nj < NF; ++nj) {
            const int col = n0 + wn * (NF * 16) + nj * 16 + r16;
            const int rowb = m0 + wm * 128 + mi * 16 + q * 4;
            const float bv = (col < Ntrue) ? bias[col] : 0.f;
            #pragma unroll
            for (int r = 0; r < 4; ++r) {
                float v = acc[mi][nj][r] + bv;
                if (relu_flag) v = fmaxf(v, 0.f);
                if (Cf) {
                    if (col < Ntrue) Cf[(size_t)(rowb + r) * ldc + col] = v;
                } else {
                    const size_t idx = poff(rowb + r, col, ldc);  // packed dest
                    ushort_t h = f2bf(v);
                    Chi[idx] = h;
                    Clo[idx] = f2bf(v - bf2f(h));
                }
            }
        }
    }
}

// ---- plain bf16 single pass: quad-buffered, 2-tile-ahead prefetch ----
template <int BN>
__global__ __launch_bounds__(512, 2) void gemm_bf16k(
    const ushort_t* __restrict__ Ahi, const ushort_t* __restrict__ Bhi,
    const float* __restrict__ bias,
    float* __restrict__ Cf, ushort_t* __restrict__ Chi,
    int K, int Ntrue, int ldc, int relu_flag)
{
    static_assert(BN == 256 || BN == 128, "BN");
    constexpr int BSLAB = BN / 128;
    constexpr int NF = BN / 64;
    constexpr int SH = 2 + BSLAB;          // issues per tile

    __shared__ __align__(16) ushort_t sA[4][8192];
    __shared__ __align__(16) ushort_t sB[4][BSLAB * 4096];

    const int tid = threadIdx.x;
    int bx, by;
    xcd_remap(bx, by);
    const int m0 = by * 256;
    const int n0 = bx * BN;

    const int lane = tid & 63, wave = tid >> 6;
    const int wm = wave >> 2, wn = wave & 3;
    const int q = lane >> 4, r16 = lane & 15;
    const int wofs = wave * 512;

    const size_t bstr = (size_t)(K >> 5) * 4096;
    const ushort_t* gA = Ahi + (size_t)(2 * by) * bstr + tid * 8;
    const ushort_t* gB = Bhi + (size_t)(BSLAB * bx) * bstr + tid * 8;

    int aoff[8], boff[NF];
    #pragma unroll
    for (int mi = 0; mi < 8; ++mi)
        aoff[mi] = wm * 4096 + (q * 128 + mi * 16 + r16) * 8;
    #pragma unroll
    for (int nj = 0; nj < NF; ++nj) {
        const int col = wn * (NF * 16) + nj * 16 + r16;
        boff[nj] = (col >> 7) * 4096 + (q * 128 + (col & 127)) * 8;
    }

    f32x4 acc[8][NF];
    #pragma unroll
    for (int mi = 0; mi < 8; ++mi)
        #pragma unroll
        for (int nj = 0; nj < NF; ++nj) acc[mi][nj] = (f32x4)(0.f);

    const int NT = K >> 5;

    // prologue: stage tiles 0 and 1
    #pragma unroll
    for (int tt = 0; tt < 2; ++tt) {
        const size_t ko = (size_t)tt * 4096;
        ll16(gA + ko, &sA[tt][wofs]);
        ll16(gA + bstr + ko, &sA[tt][4096 + wofs]);
        ll16(gB + ko, &sB[tt][wofs]);
        if constexpr (BSLAB == 2) ll16(gB + bstr + ko, &sB[tt][4096 + wofs]);
    }

    bf16x8 ah[8], bh[NF];
    for (int t = 0; t < NT - 1; ++t) {
        const int c = t & 3;
        wait_vmcnt<SH>();                  // tile t landed; t+1 may fly
        __builtin_amdgcn_s_barrier();
        #pragma unroll
        for (int mi = 0; mi < 8; ++mi) ah[mi] = *(const bf16x8*)(&sA[c][aoff[mi]]);
        #pragma unroll
        for (int nj = 0; nj < NF; ++nj) bh[nj] = *(const bf16x8*)(&sB[c][boff[nj]]);
        if (t + 2 < NT) {
            const int c2 = (t + 2) & 3;
            const size_t ko = (size_t)(t + 2) * 4096;
            ll16(gA + ko, &sA[c2][wofs]);
            ll16(gA + bstr + ko, &sA[c2][4096 + wofs]);
            ll16(gB + ko, &sB[c2][wofs]);
            if constexpr (BSLAB == 2) ll16(gB + bstr + ko, &sB[c2][4096 + wofs]);
        }
        __builtin_amdgcn_sched_barrier(0);
        __builtin_amdgcn_s_setprio(1);
        #pragma unroll
        for (int nj = 0; nj < NF; ++nj)
            #pragma unroll
            for (int mi = 0; mi < 8; ++mi)
                acc[mi][nj] = __builtin_amdgcn_mfma_f32_16x16x32_bf16(ah[mi], bh[nj], acc[mi][nj], 0, 0, 0);
        __builtin_amdgcn_s_setprio(0);
    }
    {   // tail tile NT-1
        const int c = (NT - 1) & 3;
        wait_vmcnt<0>();
        __builtin_amdgcn_s_barrier();
        #pragma unroll
        for (int mi = 0; mi < 8; ++mi) ah[mi] = *(const bf16x8*)(&sA[c][aoff[mi]]);
        #pragma unroll
        for (int nj = 0; nj < NF; ++nj) bh[nj] = *(const bf16x8*)(&sB[c][boff[nj]]);
        __builtin_amdgcn_s_setprio(1);
        #pragma unroll
        for (int nj = 0; nj < NF; ++nj)
            #pragma unroll
            for (int mi = 0; mi < 8; ++mi)
                acc[mi][nj] = __builtin_amdgcn_mfma_f32_16x16x32_bf16(ah[mi], bh[nj], acc[mi][nj], 0, 0, 0);
        __builtin_amdgcn_s_setprio(0);
    }

    #pragma unroll
    for (int mi = 0; mi < 8; ++mi) {
        #pragma unroll
        for (int nj = 0; nj < NF; ++nj) {
            const int col = n0 + wn * (NF * 16) + nj * 16 + r16;
            const int rowb = m0 + wm * 128 + mi * 16 + q * 4;
            const float bv = (col < Ntrue) ? bias[col] : 0.f;
            #pragma unroll
            for (int r = 0; r < 4; ++r) {
                float v = acc[mi][nj][r] + bv;
                if (relu_flag) v = fmaxf(v, 0.f);
                if (Cf) {
                    if (col < Ntrue) Cf[(size_t)(rowb + r) * ldc + col] = v;
                } else {
                    const size_t idx = poff(rowb + r, col, ldc);
                    Chi[idx] = f2bf(v);
                }
            }
        }
    }
}

// ---- finalize: per-row confidence cascade + output select ----
// confident <=> max softmax prob > 0.01 <=> sum(exp(l - max)) < 100
// out holds p1. If conf1: keep. Else if conf2: out = p2 row. Else: out = p3.
__global__ __launch_bounds__(256) void finalize_kernel(
    float* __restrict__ out, const float* __restrict__ p2,
    const float* __restrict__ p3, int N)
{
    __shared__ float rm[4];
    __shared__ float rs[4];
    const int b = blockIdx.x;
    const int wv = threadIdx.x >> 6, ln = threadIdx.x & 63;

    // conf on p1 (== out row)
    const float* row = out + (size_t)b * N;
    float m = -3.0e38f;
    for (int c = threadIdx.x; c < N; c += 256) m = fmaxf(m, row[c]);
    #pragma unroll
    for (int off = 32; off > 0; off >>= 1) m = fmaxf(m, __shfl_down(m, off));
    if (ln == 0) rm[wv] = m;
    __syncthreads();
    m = fmaxf(fmaxf(rm[0], rm[1]), fmaxf(rm[2], rm[3]));
    float s = 0.f;
    for (int c = threadIdx.x; c < N; c += 256) s += expf(row[c] - m);
    #pragma unroll
    for (int off = 32; off > 0; off >>= 1) s += __shfl_down(s, off);
    if (ln == 0) rs[wv] = s;
    __syncthreads();
    const float tot1 = rs[0] + rs[1] + rs[2] + rs[3];
    if (tot1 < 100.0f) return;             // stage-1 exit: keep p1

    // conf on p2
    __syncthreads();                       // protect rm/rs reuse
    const float* row2 = p2 + (size_t)b * N;
    m = -3.0e38f;
    for (int c = threadIdx.x; c < N; c += 256) m = fmaxf(m, row2[c]);
    #pragma unroll
    for (int off = 32; off > 0; off >>= 1) m = fmaxf(m, __shfl_down(m, off));
    if (ln == 0) rm[wv] = m;
    __syncthreads();
    m = fmaxf(fmaxf(rm[0], rm[1]), fmaxf(rm[2], rm[3]));
    s = 0.f;
    for (int c = threadIdx.x; c < N; c += 256) s += expf(row2[c] - m);
    #pragma unroll
    for (int off = 32; off > 0; off >>= 1) s += __shfl_down(s, off);
    if (ln == 0) rs[wv] = s;
    __syncthreads();
    const float tot2 = rs[0] + rs[1] + rs[2] + rs[3];

    const float* src = (tot2 < 100.0f) ? row2 : (p3 + (size_t)b * N);
    float* dst = out + (size_t)b * N;
    // N == 1000: 250 float4 per row, rows 16B-aligned (4000B stride)
    for (int c4 = threadIdx.x; c4 < (N >> 2); c4 += 256)
        ((float4*)dst)[c4] = ((const float4*)src)[c4];
    for (int c = (N & ~3) + threadIdx.x; c < N; c += 256) dst[c] = src[c];
}

extern "C" void kernel_launch(void* const* d_in, const int* in_sizes, int n_in,
                              void* d_out, int out_size, void* d_ws, size_t ws_size,
                              hipStream_t stream)
{
    const float* x   = (const float*)d_in[0];
    const float* W1  = (const float*)d_in[1];
    const float* b1  = (const float*)d_in[2];
    const float* W2  = (const float*)d_in[3];
    const float* b2  = (const float*)d_in[4];
    const float* W3  = (const float*)d_in[5];
    const float* b3  = (const float*)d_in[6];
    const float* H1w = (const float*)d_in[7];
    const float* H1b = (const float*)d_in[8];
    const float* H2w = (const float*)d_in[9];
    const float* H2b = (const float*)d_in[10];
    const float* Fw  = (const float*)d_in[11];
    const float* Fb  = (const float*)d_in[12];
    float* out = (float*)d_out;

    const int B = 8192, D = 2048, Hh = 2048, Cc = 1000;

    // ---- workspace carve (~184 MB; ushort units) ----
    ushort_t* xhi  = (ushort_t*)d_ws;             // B*D packed x-hi   (-> h2-hi)
    ushort_t* xlo  = xhi + (size_t)B * D;         // B*D packed x-lo   (-> h2-lo -> p3 fp32)
    ushort_t* h1hi = xlo + (size_t)B * D;         // B*H packed h1-hi  (-> h3-hi)
    ushort_t* h1lo = h1hi + (size_t)B * Hh;       // B*H packed h1-lo
    ushort_t* W0hi = h1lo + (size_t)B * Hh;       // 2048x2048 packed (W1t/W2t/W3t)
    ushort_t* W0lo = W0hi + (size_t)Hh * Hh;
    ushort_t* W1thi = W0lo + (size_t)Hh * Hh;     // 1024x2048 packed (heads)
    ushort_t* W1tlo = W1thi + (size_t)1024 * Hh;
    float* p2 = (float*)(W1tlo + (size_t)1024 * Hh);  // B*Cc fp32

    ushort_t* h2hi = xhi;  ushort_t* h2lo = xlo;   // x dead after stage-1 backbone
    ushort_t* h3hi = h1hi;                          // h1 dead after stage-2 backbone
    float* p3 = (float*)xlo;                        // h2-lo dead after stage-2 head

    dim3 blk(256);
    dim3 blk5(512);
    const dim3 gBB(Hh / 256, B / 256);   // backbone GEMM: 256x256 tiles (8, 32)
    const dim3 gHD(1024 / 128, B / 256); // head GEMM: 256x128 tiles (8, 32)
    const dim3 gT2(64, 64);   // tsplit 2048x2048
    const dim3 gTH(32, 64);   // tsplit head (Npad=1024)

    // Stage 1
    split_kernel<<<dim3(B * D / 8 / 256), blk, 0, stream>>>(x, xhi, xlo, D);
    tsplit_kernel<<<gT2, blk, 0, stream>>>(W1, W0hi, W0lo, D, Hh, 1);
    gemm_split3<256><<<gBB, blk5, 0, stream>>>(xhi, xlo, W0hi, W0lo, b1,
                                               nullptr, h1hi, h1lo, D, Hh, Hh, 1);
    tsplit_kernel<<<gTH, blk, 0, stream>>>(H1w, W1thi, W1tlo, Hh, Cc, 1);
    gemm_split3<128><<<gHD, blk5, 0, stream>>>(h1hi, h1lo, W1thi, W1tlo, H1b,
                                               out, nullptr, nullptr, Hh, Cc, Cc, 0);

    // Stage 2 (all rows; exits are rare so dense is cheaper than compaction)
    tsplit_kernel<<<gT2, blk, 0, stream>>>(W2, W0hi, W0lo, Hh, Hh, 1);
    gemm_split3<256><<<gBB, blk5, 0, stream>>>(h1hi, h1lo, W0hi, W0lo, b2,
                                               nullptr, h2hi, h2lo, Hh, Hh, Hh, 1);
    tsplit_kernel<<<gTH, blk, 0, stream>>>(H2w, W1thi, W1tlo, Hh, Cc, 1);
    gemm_split3<128><<<gHD, blk5, 0, stream>>>(h2hi, h2lo, W1thi, W1tlo, H2b,
                                               p2, nullptr, nullptr, Hh, Cc, Cc, 0);

    // Stage 3 (all rows; plain bf16 single pass — p3 feeds no decision)
    tsplit_kernel<<<gT2, blk, 0, stream>>>(W3, W0hi, nullptr, Hh, Hh, 0);
    gemm_bf16k<256><<<gBB, blk5, 0, stream>>>(h2hi, W0hi, b3,
                                              nullptr, h3hi, Hh, Hh, Hh, 1);
    tsplit_kernel<<<gTH, blk, 0, stream>>>(Fw, W1thi, nullptr, Hh, Cc, 0);
    gemm_bf16k<128><<<gHD, blk5, 0, stream>>>(h3hi, W1thi, Fb,
                                              p3, nullptr, Hh, Cc, Cc, 0);

    // Merge: per-row confidence cascade, select p1/p2/p3 into out
    finalize_kernel<<<dim3(B), blk, 0, stream>>>(out, p2, p3, Cc);
}